// Round 1
// baseline (163.078 us; speedup 1.0000x reference)
//
#include <hip/hip_runtime.h>

#define GD 128
#define GD3 (GD*GD*GD)

typedef __attribute__((ext_vector_type(8))) __bf16 bf16x8;
typedef __attribute__((ext_vector_type(4))) float f32x4;
typedef __attribute__((ext_vector_type(4))) unsigned int u32x4;

__device__ __forceinline__ unsigned short f2bf(float x) {
  unsigned int u = __builtin_bit_cast(unsigned int, x);
  unsigned int r = (u + 0x7FFFu + ((u >> 16) & 1u)) >> 16;  // RNE
  return (unsigned short)r;
}

__global__ void k_init_grid(int* __restrict__ g) {
  int i = blockIdx.x * 256 + threadIdx.x;
  if (i < GD3) g[i] = -1;
}

__global__ void k_scatter(const int* __restrict__ coords, int* __restrict__ g, int n) {
  int i = blockIdx.x * 256 + threadIdx.x;
  if (i >= n) return;
  int x = coords[3*i], y = coords[3*i+1], z = coords[3*i+2];
  g[(x << 14) | (y << 7) | z] = i;
}

// Pack w2 (27,16,32) and w3 (27,32,64) into MFMA B-fragment order, bf16.
// Layout: wpk[k][chunk][lane][j], value = W[k][ci][co], ci=(lane>>4)*8+j, co=chunk*16+(lane&15).
// w2 zero-padded in ci to K=32.
__global__ void k_wpack(const float* __restrict__ w2, const float* __restrict__ w3,
                        unsigned short* __restrict__ w2pk, unsigned short* __restrict__ w3pk) {
  int gid = blockIdx.x * 256 + threadIdx.x;
  if (gid < 3456) {                      // 27 * 2 chunks * 64 lanes
    int k = gid >> 7, rem = gid & 127, c = rem >> 6, l = rem & 63;
    int gq = l >> 4, col = l & 15;
    #pragma unroll
    for (int j = 0; j < 8; j++) {
      int ci = gq * 8 + j, co = c * 16 + col;
      float v = (ci < 16) ? w2[(k * 16 + ci) * 32 + co] : 0.f;
      w2pk[gid * 8 + j] = f2bf(v);
    }
  } else if (gid < 3456 + 6912) {        // 27 * 4 chunks * 64 lanes
    int g2 = gid - 3456;
    int k = g2 >> 8, rem = g2 & 255, c = rem >> 6, l = rem & 63;
    int gq = l >> 4, col = l & 15;
    #pragma unroll
    for (int j = 0; j < 8; j++) {
      int ci = gq * 8 + j, co = c * 16 + col;
      float v = w3[(k * 32 + ci) * 64 + co];
      w3pk[g2 * 8 + j] = f2bf(v);
    }
  }
}

// Rulebook build (k-major) fused with conv1 (1 -> 16 ch, fp32 VALU).
// x1 written as bf16 rows padded to 32 channels (upper 16 zero) for MFMA K=32.
__global__ void k_nbr_conv1(const int* __restrict__ coords, const float* __restrict__ feats,
                            const float* __restrict__ w1, const int* __restrict__ grid,
                            int* __restrict__ nbr, unsigned short* __restrict__ x1bf, int n) {
  int i = blockIdx.x * 256 + threadIdx.x;
  if (i >= n) return;
  int x = coords[3*i], y = coords[3*i+1], z = coords[3*i+2];
  float acc[16];
  #pragma unroll
  for (int c = 0; c < 16; c++) acc[c] = 0.f;
  #pragma unroll
  for (int k = 0; k < 27; k++) {
    const int dx = k/9 - 1, dy = (k/3)%3 - 1, dz = k%3 - 1;
    int nx = x+dx, ny = y+dy, nz = z+dz;
    int idx = -1;
    if (((unsigned)nx < 128u) && ((unsigned)ny < 128u) && ((unsigned)nz < 128u))
      idx = grid[(nx << 14) | (ny << 7) | nz];
    nbr[k*n + i] = idx;
    float f = 0.f;
    if (idx >= 0) f = feats[idx];
    #pragma unroll
    for (int c = 0; c < 16; c++) acc[c] = fmaf(f, w1[k*16+c], acc[c]);
  }
  u32x4 d0, d1, dz4 = {0u,0u,0u,0u};
  d0.x = (unsigned)f2bf(acc[0])  | ((unsigned)f2bf(acc[1])  << 16);
  d0.y = (unsigned)f2bf(acc[2])  | ((unsigned)f2bf(acc[3])  << 16);
  d0.z = (unsigned)f2bf(acc[4])  | ((unsigned)f2bf(acc[5])  << 16);
  d0.w = (unsigned)f2bf(acc[6])  | ((unsigned)f2bf(acc[7])  << 16);
  d1.x = (unsigned)f2bf(acc[8])  | ((unsigned)f2bf(acc[9])  << 16);
  d1.y = (unsigned)f2bf(acc[10]) | ((unsigned)f2bf(acc[11]) << 16);
  d1.z = (unsigned)f2bf(acc[12]) | ((unsigned)f2bf(acc[13]) << 16);
  d1.w = (unsigned)f2bf(acc[14]) | ((unsigned)f2bf(acc[15]) << 16);
  u32x4* dst = (u32x4*)(x1bf + (size_t)i * 32);
  dst[0] = d0; dst[1] = d1; dst[2] = dz4; dst[3] = dz4;
}

// Gather-MFMA conv layer. K=32 (bf16 rows), N = CHUNKS*16 output channels.
// Each wave owns 32 points (two 16-row M-tiles). k loop is wave-uniform so the
// packed-weight B-fragment address is uniform+lane. CHUNKS==4 fuses the 64->3 head.
template<int CHUNKS>
__launch_bounds__(256)
__global__ void k_conv(const int* __restrict__ nbr, const unsigned short* __restrict__ xin,
                       const unsigned short* __restrict__ wpk, unsigned short* __restrict__ xout,
                       const float* __restrict__ wm, const float* __restrict__ bm,
                       float* __restrict__ outf, int n) {
  const int lane = threadIdx.x & 63;
  const int wid = blockIdx.x * 4 + (threadIdx.x >> 6);
  const int base = wid * 32;
  if (base >= n) return;
  const int col = lane & 15, grp = lane >> 4;
  const int ra = base + col, rb = base + 16 + col;
  f32x4 acc[2][CHUNKS];
  #pragma unroll
  for (int t = 0; t < 2; t++)
    #pragma unroll
    for (int c = 0; c < CHUNKS; c++) acc[t][c] = (f32x4){0.f,0.f,0.f,0.f};
  const bf16x8 az = __builtin_bit_cast(bf16x8, (u32x4){0u,0u,0u,0u});

  for (int k = 0; k < 27; k++) {
    int ia = (ra < n) ? nbr[k*n + ra] : -1;
    int ib = (rb < n) ? nbr[k*n + rb] : -1;
    if (!__any((ia >= 0) || (ib >= 0))) continue;
    bf16x8 a0 = az, a1 = az;
    if (ia >= 0) a0 = *(const bf16x8*)(xin + (size_t)ia * 32 + grp * 8);
    if (ib >= 0) a1 = *(const bf16x8*)(xin + (size_t)ib * 32 + grp * 8);
    const unsigned short* wk = wpk + ((size_t)(k * CHUNKS) * 64 + lane) * 8;
    #pragma unroll
    for (int c = 0; c < CHUNKS; c++) {
      bf16x8 b = *(const bf16x8*)(wk + (size_t)c * 512);
      acc[0][c] = __builtin_amdgcn_mfma_f32_16x16x32_bf16(a0, b, acc[0][c], 0, 0, 0);
      acc[1][c] = __builtin_amdgcn_mfma_f32_16x16x32_bf16(a1, b, acc[1][c], 0, 0, 0);
    }
  }

  if constexpr (CHUNKS == 2) {
    // conv2 epilogue: store x2 as bf16 rows [n][32]
    #pragma unroll
    for (int t = 0; t < 2; t++)
      #pragma unroll
      for (int c = 0; c < CHUNKS; c++)
        #pragma unroll
        for (int r = 0; r < 4; r++) {
          int m = base + t*16 + grp*4 + r;
          if (m < n) xout[(size_t)m * 32 + c*16 + col] = f2bf(acc[t][c][r]);
        }
  } else {
    // conv3 epilogue: fused head x3 @ wm + bm, reduce 64 channels across the 16-lane group
    float wmv[CHUNKS][3];
    #pragma unroll
    for (int c = 0; c < CHUNKS; c++)
      #pragma unroll
      for (int j = 0; j < 3; j++) wmv[c][j] = wm[(c*16 + col)*3 + j];
    float bb0 = bm[0], bb1 = bm[1], bb2 = bm[2];
    #pragma unroll
    for (int t = 0; t < 2; t++)
      #pragma unroll
      for (int r = 0; r < 4; r++) {
        float p0 = 0.f, p1 = 0.f, p2 = 0.f;
        #pragma unroll
        for (int c = 0; c < CHUNKS; c++) {
          float v = acc[t][c][r];
          p0 = fmaf(v, wmv[c][0], p0);
          p1 = fmaf(v, wmv[c][1], p1);
          p2 = fmaf(v, wmv[c][2], p2);
        }
        #pragma unroll
        for (int msk = 1; msk <= 8; msk <<= 1) {
          p0 += __shfl_xor(p0, msk);
          p1 += __shfl_xor(p1, msk);
          p2 += __shfl_xor(p2, msk);
        }
        if (col == 0) {
          int m = base + t*16 + grp*4 + r;
          if (m < n) {
            outf[m*3+0] = p0 + bb0;
            outf[m*3+1] = p1 + bb1;
            outf[m*3+2] = p2 + bb2;
          }
        }
      }
  }
}

extern "C" void kernel_launch(void* const* d_in, const int* in_sizes, int n_in,
                              void* d_out, int out_size, void* d_ws, size_t ws_size,
                              hipStream_t stream) {
  (void)n_in; (void)out_size; (void)ws_size;
  const int*   coords = (const int*)d_in[0];
  const float* feats  = (const float*)d_in[1];
  const float* w1     = (const float*)d_in[2];
  const float* w2     = (const float*)d_in[3];
  const float* w3     = (const float*)d_in[4];
  const float* wm     = (const float*)d_in[5];
  const float* bm     = (const float*)d_in[6];
  float* outf = (float*)d_out;
  const int n = in_sizes[0] / 3;

  char* ws = (char*)d_ws;
  size_t off = 0;
  int* grid = (int*)(ws + off); off += (size_t)GD3 * 4;
  int* nbr  = (int*)(ws + off); off += (size_t)27 * n * 4;
  off = (off + 255) & ~(size_t)255;
  unsigned short* x1bf = (unsigned short*)(ws + off); off += (size_t)n * 32 * 2;
  off = (off + 255) & ~(size_t)255;
  unsigned short* x2bf = (unsigned short*)(ws + off); off += (size_t)n * 32 * 2;
  off = (off + 255) & ~(size_t)255;
  unsigned short* w2pk = (unsigned short*)(ws + off); off += (size_t)3456 * 8 * 2;
  off = (off + 255) & ~(size_t)255;
  unsigned short* w3pk = (unsigned short*)(ws + off); off += (size_t)6912 * 8 * 2;

  hipLaunchKernelGGL(k_init_grid, dim3((GD3 + 255) / 256), dim3(256), 0, stream, grid);
  hipLaunchKernelGGL(k_scatter, dim3((n + 255) / 256), dim3(256), 0, stream, coords, grid, n);
  hipLaunchKernelGGL(k_wpack, dim3(41), dim3(256), 0, stream, w2, w3, w2pk, w3pk);
  hipLaunchKernelGGL(k_nbr_conv1, dim3((n + 255) / 256), dim3(256), 0, stream,
                     coords, feats, w1, grid, nbr, x1bf, n);
  const int waves = (n + 31) / 32;
  const int cblocks = (waves + 3) / 4;
  hipLaunchKernelGGL((k_conv<2>), dim3(cblocks), dim3(256), 0, stream,
                     nbr, x1bf, w2pk, x2bf, nullptr, nullptr, nullptr, n);
  hipLaunchKernelGGL((k_conv<4>), dim3(cblocks), dim3(256), 0, stream,
                     nbr, x2bf, w3pk, nullptr, wm, bm, outf, n);
}

// Round 2
// 151.179 us; speedup vs baseline: 1.0787x; 1.0787x over previous
//
#include <hip/hip_runtime.h>

#define GD 128
#define GD3 (GD*GD*GD)
#define KP 29   // 27 real offsets + 2 zero-pad planes so the pipeline can prefetch unconditionally

typedef __attribute__((ext_vector_type(8))) __bf16 bf16x8;
typedef __attribute__((ext_vector_type(4))) float f32x4;
typedef __attribute__((ext_vector_type(4))) unsigned int u32x4;

__device__ __forceinline__ unsigned short f2bf(float x) {
  unsigned int u = __builtin_bit_cast(unsigned int, x);
  unsigned int r = (u + 0x7FFFu + ((u >> 16) & 1u)) >> 16;  // RNE
  return (unsigned short)r;
}

__global__ void k_init_grid(int* __restrict__ g) {
  int i = blockIdx.x * 256 + threadIdx.x;
  if (i < GD3) g[i] = -1;
}

__global__ void k_scatter(const int* __restrict__ coords, int* __restrict__ g, int n) {
  int i = blockIdx.x * 256 + threadIdx.x;
  if (i >= n) return;
  int x = coords[3*i], y = coords[3*i+1], z = coords[3*i+2];
  g[(x << 14) | (y << 7) | z] = i;
}

// Pack w2 (27,16,32) and w3 (27,32,64) into MFMA B-fragment order, bf16, padded to KP ks
// (pad ks zeroed so pipeline-prefetched B for k=27 is finite).
// wpk[k][chunk][lane][j] = W[k][ci][co], ci=(lane>>4)*8+j, co=chunk*16+(lane&15).
// Two leftover threads zero row n of x1bf / x2bf (the "inactive neighbor" row).
__global__ void k_wpack(const float* __restrict__ w2, const float* __restrict__ w3,
                        unsigned short* __restrict__ w2pk, unsigned short* __restrict__ w3pk,
                        unsigned short* __restrict__ x1bf, unsigned short* __restrict__ x2bf,
                        int n) {
  int gid = blockIdx.x * 256 + threadIdx.x;
  const int N2 = KP * 2 * 64;          // 3712 items for w2pk
  const int N3 = KP * 4 * 64;          // 7424 items for w3pk
  if (gid < N2) {
    int k = gid >> 7, rem = gid & 127, c = rem >> 6, l = rem & 63;
    int gq = l >> 4, col = l & 15;
    #pragma unroll
    for (int j = 0; j < 8; j++) {
      int ci = gq * 8 + j, co = c * 16 + col;
      float v = (k < 27 && ci < 16) ? w2[(k * 16 + ci) * 32 + co] : 0.f;
      w2pk[gid * 8 + j] = f2bf(v);
    }
  } else if (gid < N2 + N3) {
    int g2 = gid - N2;
    int k = g2 >> 8, rem = g2 & 255, c = rem >> 6, l = rem & 63;
    int gq = l >> 4, col = l & 15;
    #pragma unroll
    for (int j = 0; j < 8; j++) {
      int ci = gq * 8 + j, co = c * 16 + col;
      float v = (k < 27) ? w3[(k * 32 + ci) * 64 + co] : 0.f;
      w3pk[g2 * 8 + j] = f2bf(v);
    }
  } else if (gid == N2 + N3) {
    u32x4 z = {0u,0u,0u,0u};
    u32x4* d = (u32x4*)(x1bf + (size_t)n * 32);
    d[0] = z; d[1] = z; d[2] = z; d[3] = z;
  } else if (gid == N2 + N3 + 1) {
    u32x4 z = {0u,0u,0u,0u};
    u32x4* d = (u32x4*)(x2bf + (size_t)n * 32);
    d[0] = z; d[1] = z; d[2] = z; d[3] = z;
  }
}

// Rulebook build (k-major, idx pre-clamped: inactive -> n, the zero row) fused with conv1.
// Planes 27/28 point at the zero row (pipeline prefetch reads them harmlessly).
__global__ void k_nbr_conv1(const int* __restrict__ coords, const float* __restrict__ feats,
                            const float* __restrict__ w1, const int* __restrict__ grid,
                            int* __restrict__ nbr, unsigned short* __restrict__ x1bf,
                            int n, int npad) {
  int i = blockIdx.x * 256 + threadIdx.x;
  if (i >= npad) return;
  if (i >= n) {
    #pragma unroll
    for (int k = 0; k < KP; k++) nbr[k*npad + i] = n;
    return;
  }
  int x = coords[3*i], y = coords[3*i+1], z = coords[3*i+2];
  float acc[16];
  #pragma unroll
  for (int c = 0; c < 16; c++) acc[c] = 0.f;
  #pragma unroll
  for (int k = 0; k < 27; k++) {
    const int dx = k/9 - 1, dy = (k/3)%3 - 1, dz = k%3 - 1;
    int nx = x+dx, ny = y+dy, nz = z+dz;
    int idx = -1;
    if (((unsigned)nx < 128u) && ((unsigned)ny < 128u) && ((unsigned)nz < 128u))
      idx = grid[(nx << 14) | (ny << 7) | nz];
    nbr[k*npad + i] = (idx >= 0) ? idx : n;
    float f = 0.f;
    if (idx >= 0) f = feats[idx];
    #pragma unroll
    for (int c = 0; c < 16; c++) acc[c] = fmaf(f, w1[k*16+c], acc[c]);
  }
  nbr[27*npad + i] = n;
  nbr[28*npad + i] = n;
  u32x4 d0, d1, dz4 = {0u,0u,0u,0u};
  d0.x = (unsigned)f2bf(acc[0])  | ((unsigned)f2bf(acc[1])  << 16);
  d0.y = (unsigned)f2bf(acc[2])  | ((unsigned)f2bf(acc[3])  << 16);
  d0.z = (unsigned)f2bf(acc[4])  | ((unsigned)f2bf(acc[5])  << 16);
  d0.w = (unsigned)f2bf(acc[6])  | ((unsigned)f2bf(acc[7])  << 16);
  d1.x = (unsigned)f2bf(acc[8])  | ((unsigned)f2bf(acc[9])  << 16);
  d1.y = (unsigned)f2bf(acc[10]) | ((unsigned)f2bf(acc[11]) << 16);
  d1.z = (unsigned)f2bf(acc[12]) | ((unsigned)f2bf(acc[13]) << 16);
  d1.w = (unsigned)f2bf(acc[14]) | ((unsigned)f2bf(acc[15]) << 16);
  u32x4* dst = (u32x4*)(x1bf + (size_t)i * 32);
  dst[0] = d0; dst[1] = d1; dst[2] = dz4; dst[3] = dz4;
}

// Gather-MFMA conv layer, 2-stage software pipeline:
// per iteration k: issue nbr[k+2] loads, issue gathers+B for k+1, MFMA on k's staged data.
// All gathers are unconditional (inactive -> zero row n). No branches in the loop.
template<int CHUNKS>
__launch_bounds__(256)
__global__ void k_conv(const int* __restrict__ nbr, const unsigned short* __restrict__ xin,
                       const unsigned short* __restrict__ wpk, unsigned short* __restrict__ xout,
                       const float* __restrict__ wm, const float* __restrict__ bm,
                       float* __restrict__ outf, int n, int npad) {
  const int lane = threadIdx.x & 63;
  const int wid = blockIdx.x * 4 + (threadIdx.x >> 6);
  const int base = wid * 32;
  if (base >= npad) return;
  const int col = lane & 15, grp = lane >> 4;
  const int ra = base + col, rb = base + 16 + col;
  const unsigned short* xin_g = xin + grp * 8;

  f32x4 acc[2][CHUNKS];
  #pragma unroll
  for (int t = 0; t < 2; t++)
    #pragma unroll
    for (int c = 0; c < CHUNKS; c++) acc[t][c] = (f32x4){0.f,0.f,0.f,0.f};

  // prologue: stage k=0 data, k=1 indices
  int ja = nbr[ra], jb = nbr[rb];
  bf16x8 a0 = *(const bf16x8*)(xin_g + (size_t)ja * 32);
  bf16x8 a1 = *(const bf16x8*)(xin_g + (size_t)jb * 32);
  bf16x8 b[CHUNKS];
  #pragma unroll
  for (int c = 0; c < CHUNKS; c++)
    b[c] = *(const bf16x8*)(wpk + ((size_t)(c * 64 + lane)) * 8);
  ja = nbr[npad + ra]; jb = nbr[npad + rb];

  for (int k = 0; k < 27; ++k) {
    // stage 1: indices for k+2 (planes exist through KP-1=28)
    int ka = nbr[(k + 2) * npad + ra];
    int kb = nbr[(k + 2) * npad + rb];
    // stage 2: gathers + B for k+1 (pad plane -> zero row; pad B -> zeros)
    bf16x8 na0 = *(const bf16x8*)(xin_g + (size_t)ja * 32);
    bf16x8 na1 = *(const bf16x8*)(xin_g + (size_t)jb * 32);
    bf16x8 nb[CHUNKS];
    #pragma unroll
    for (int c = 0; c < CHUNKS; c++)
      nb[c] = *(const bf16x8*)(wpk + ((size_t)(((k + 1) * CHUNKS + c) * 64 + lane)) * 8);
    // stage 3: MFMA on k's data
    #pragma unroll
    for (int c = 0; c < CHUNKS; c++) {
      acc[0][c] = __builtin_amdgcn_mfma_f32_16x16x32_bf16(a0, b[c], acc[0][c], 0, 0, 0);
      acc[1][c] = __builtin_amdgcn_mfma_f32_16x16x32_bf16(a1, b[c], acc[1][c], 0, 0, 0);
    }
    // rotate
    a0 = na0; a1 = na1; ja = ka; jb = kb;
    #pragma unroll
    for (int c = 0; c < CHUNKS; c++) b[c] = nb[c];
  }

  if constexpr (CHUNKS == 2) {
    #pragma unroll
    for (int t = 0; t < 2; t++)
      #pragma unroll
      for (int c = 0; c < CHUNKS; c++)
        #pragma unroll
        for (int r = 0; r < 4; r++) {
          int m = base + t*16 + grp*4 + r;
          if (m < n) xout[(size_t)m * 32 + c*16 + col] = f2bf(acc[t][c][r]);
        }
  } else {
    float wmv[CHUNKS][3];
    #pragma unroll
    for (int c = 0; c < CHUNKS; c++)
      #pragma unroll
      for (int j = 0; j < 3; j++) wmv[c][j] = wm[(c*16 + col)*3 + j];
    float bb0 = bm[0], bb1 = bm[1], bb2 = bm[2];
    #pragma unroll
    for (int t = 0; t < 2; t++)
      #pragma unroll
      for (int r = 0; r < 4; r++) {
        float p0 = 0.f, p1 = 0.f, p2 = 0.f;
        #pragma unroll
        for (int c = 0; c < CHUNKS; c++) {
          float v = acc[t][c][r];
          p0 = fmaf(v, wmv[c][0], p0);
          p1 = fmaf(v, wmv[c][1], p1);
          p2 = fmaf(v, wmv[c][2], p2);
        }
        #pragma unroll
        for (int msk = 1; msk <= 8; msk <<= 1) {
          p0 += __shfl_xor(p0, msk);
          p1 += __shfl_xor(p1, msk);
          p2 += __shfl_xor(p2, msk);
        }
        if (col == 0) {
          int m = base + t*16 + grp*4 + r;
          if (m < n) {
            outf[m*3+0] = p0 + bb0;
            outf[m*3+1] = p1 + bb1;
            outf[m*3+2] = p2 + bb2;
          }
        }
      }
  }
}

extern "C" void kernel_launch(void* const* d_in, const int* in_sizes, int n_in,
                              void* d_out, int out_size, void* d_ws, size_t ws_size,
                              hipStream_t stream) {
  (void)n_in; (void)out_size; (void)ws_size;
  const int*   coords = (const int*)d_in[0];
  const float* feats  = (const float*)d_in[1];
  const float* w1     = (const float*)d_in[2];
  const float* w2     = (const float*)d_in[3];
  const float* w3     = (const float*)d_in[4];
  const float* wm     = (const float*)d_in[5];
  const float* bm     = (const float*)d_in[6];
  float* outf = (float*)d_out;
  const int n = in_sizes[0] / 3;
  const int npad = (n + 31) & ~31;

  char* ws = (char*)d_ws;
  size_t off = 0;
  int* grid = (int*)(ws + off); off += (size_t)GD3 * 4;
  int* nbr  = (int*)(ws + off); off += (size_t)KP * npad * 4;
  off = (off + 255) & ~(size_t)255;
  unsigned short* x1bf = (unsigned short*)(ws + off); off += ((size_t)n + 1) * 32 * 2;
  off = (off + 255) & ~(size_t)255;
  unsigned short* x2bf = (unsigned short*)(ws + off); off += ((size_t)n + 1) * 32 * 2;
  off = (off + 255) & ~(size_t)255;
  unsigned short* w2pk = (unsigned short*)(ws + off); off += (size_t)KP * 2 * 64 * 8 * 2;
  off = (off + 255) & ~(size_t)255;
  unsigned short* w3pk = (unsigned short*)(ws + off); off += (size_t)KP * 4 * 64 * 8 * 2;

  hipLaunchKernelGGL(k_init_grid, dim3((GD3 + 255) / 256), dim3(256), 0, stream, grid);
  hipLaunchKernelGGL(k_scatter, dim3((n + 255) / 256), dim3(256), 0, stream, coords, grid, n);
  {
    const int items = KP * 2 * 64 + KP * 4 * 64 + 2;
    hipLaunchKernelGGL(k_wpack, dim3((items + 255) / 256), dim3(256), 0, stream,
                       w2, w3, w2pk, w3pk, x1bf, x2bf, n);
  }
  hipLaunchKernelGGL(k_nbr_conv1, dim3((npad + 255) / 256), dim3(256), 0, stream,
                     coords, feats, w1, grid, nbr, x1bf, n, npad);
  const int waves = npad / 32;
  const int cblocks = (waves + 3) / 4;
  hipLaunchKernelGGL((k_conv<2>), dim3(cblocks), dim3(256), 0, stream,
                     nbr, x1bf, w2pk, x2bf, nullptr, nullptr, nullptr, n, npad);
  hipLaunchKernelGGL((k_conv<4>), dim3(cblocks), dim3(256), 0, stream,
                     nbr, x2bf, w3pk, nullptr, wm, bm, outf, n, npad);
}